// Round 3
// baseline (1250.860 us; speedup 1.0000x reference)
//
#include <hip/hip_runtime.h>
#include <hip/hip_bf16.h>
#include <math.h>

#define N_CH   192
#define HID    128
#define OQKV   384
#define NHEADS 4
#define DK     32
#define NPIX   16384
#define NB     16
#define EPS    1e-5f
#define SCALE  0.17677669529663687f  // 32^-0.5

// ---- workspace layout (float offsets) ----
#define QKV_OFF  0
#define QKV_SZ   (NB*OQKV*NPIX)            // 100,663,296 floats
#define KMAX_OFF (QKV_OFF + QKV_SZ)
#define KSUM_OFF (KMAX_OFF + NB*HID)
#define CTX_OFF  (KSUM_OFF + NB*HID)
#define CTX_SZ   (NB*NHEADS*DK*DK)         // 65536
#define WC_OFF   (CTX_OFF + CTX_SZ)
#define WC_SZ    (NB*N_CH*HID)             // 393,216
#define SUM_OFF  (WC_OFF + WC_SZ)          // 32 doubles (as 64 floats), even offset
#define SUM_SZ   64
#define MURS_OFF (SUM_OFF + SUM_SZ)        // mu[16], rs[16]

// ---- K0: zero context + LN sums ----
__global__ __launch_bounds__(256) void k_zero(float* __restrict__ ws) {
    int idx = blockIdx.x * 256 + threadIdx.x;
    if (idx < CTX_SZ) ws[CTX_OFF + idx] = 0.f;
    if (idx < SUM_SZ) ws[SUM_OFF + idx] = 0.f;
}

// ---- K1: qkv = w_qkv @ x  (per batch, 384x16384, K=192), fp32 ----
__global__ __launch_bounds__(256) void k_qkv(const float* __restrict__ x,
                                             const float* __restrict__ wqkv,
                                             float* __restrict__ qkv) {
    __shared__ float Ws[16][128];
    __shared__ float Xs[16][132];
    int t = threadIdx.x;
    int tx = t & 15, ty = t >> 4;
    int b  = blockIdx.z;
    int o0 = blockIdx.y * 128;
    int n0 = blockIdx.x * 128;
    const float* xb = x + (size_t)b * N_CH * NPIX;

    float acc[8][8];
#pragma unroll
    for (int i = 0; i < 8; i++)
#pragma unroll
        for (int j = 0; j < 8; j++) acc[i][j] = 0.f;

    for (int k0 = 0; k0 < N_CH; k0 += 16) {
#pragma unroll
        for (int q = 0; q < 2; q++) {            // W tile: 128 o x 16 k
            int f = t + q * 256;                 // 512 float4
            int o = f >> 2, kq = f & 3;
            float4 w4 = *(const float4*)(wqkv + (size_t)(o0 + o) * N_CH + k0 + kq * 4);
            Ws[kq * 4 + 0][o] = w4.x; Ws[kq * 4 + 1][o] = w4.y;
            Ws[kq * 4 + 2][o] = w4.z; Ws[kq * 4 + 3][o] = w4.w;
        }
#pragma unroll
        for (int q = 0; q < 2; q++) {            // X tile: 16 k x 128 n
            int f = t + q * 256;
            int kk = f >> 5, n4 = f & 31;
            *(float4*)&Xs[kk][n4 * 4] =
                *(const float4*)(xb + (size_t)(k0 + kk) * NPIX + n0 + n4 * 4);
        }
        __syncthreads();
#pragma unroll
        for (int k = 0; k < 16; k++) {
            float a[8], bb[8];
            *(float4*)&a[0]  = *(float4*)&Ws[k][ty * 8];
            *(float4*)&a[4]  = *(float4*)&Ws[k][ty * 8 + 4];
            *(float4*)&bb[0] = *(float4*)&Xs[k][tx * 8];
            *(float4*)&bb[4] = *(float4*)&Xs[k][tx * 8 + 4];
#pragma unroll
            for (int i = 0; i < 8; i++)
#pragma unroll
                for (int j = 0; j < 8; j++)
                    acc[i][j] = fmaf(a[i], bb[j], acc[i][j]);
        }
        __syncthreads();
    }
    float* outb = qkv + (size_t)b * OQKV * NPIX;
#pragma unroll
    for (int i = 0; i < 8; i++) {
        int o = o0 + ty * 8 + i;
        *(float4*)(outb + (size_t)o * NPIX + n0 + tx * 8)     = *(float4*)&acc[i][0];
        *(float4*)(outb + (size_t)o * NPIX + n0 + tx * 8 + 4) = *(float4*)&acc[i][4];
    }
}

// ---- K2: k row stats (max, sumexp) over n, 2048 rows ----
__global__ __launch_bounds__(256) void k_kstats(const float* __restrict__ qkv,
                                                float* __restrict__ kmax,
                                                float* __restrict__ ksum) {
    int r = blockIdx.x;                 // b*128 + hd
    int b = r >> 7, hd = r & 127;
    const float* row = qkv + (size_t)b * OQKV * NPIX + (size_t)(HID + hd) * NPIX;
    int t = threadIdx.x;
    __shared__ float red[256];

    float m = -1e30f;
    for (int i = t; i < NPIX / 4; i += 256) {
        float4 v = ((const float4*)row)[i];
        m = fmaxf(m, fmaxf(fmaxf(v.x, v.y), fmaxf(v.z, v.w)));
    }
    red[t] = m; __syncthreads();
    for (int s = 128; s > 0; s >>= 1) { if (t < s) red[t] = fmaxf(red[t], red[t + s]); __syncthreads(); }
    m = red[0]; __syncthreads();

    float sum = 0.f;
    for (int i = t; i < NPIX / 4; i += 256) {
        float4 v = ((const float4*)row)[i];
        sum += __expf(v.x - m) + __expf(v.y - m) + __expf(v.z - m) + __expf(v.w - m);
    }
    red[t] = sum; __syncthreads();
    for (int s = 128; s > 0; s >>= 1) { if (t < s) red[t] += red[t + s]; __syncthreads(); }
    if (t == 0) { kmax[r] = m; ksum[r] = red[0]; }
}

// ---- K3: context[b,h,d,e] += sum_n softmax_k[d,n] * v[e,n] ----
__global__ __launch_bounds__(256) void k_ctx(const float* __restrict__ qkv,
                                             const float* __restrict__ kmax,
                                             const float* __restrict__ ksum,
                                             float* __restrict__ ctx) {
    int chunk = blockIdx.x, h = blockIdx.y, b = blockIdx.z;
    __shared__ float Ks[32][129];
    __shared__ float Vs[32][129];
    __shared__ float ctxp[4][32][32];
    __shared__ float kms[32], kis[32];
    int t = threadIdx.x;
    if (t < 32) {
        kms[t] = kmax[b * HID + h * DK + t];
        kis[t] = 1.0f / ksum[b * HID + h * DK + t];
    }
    __syncthreads();

    const float* kbase = qkv + (size_t)b * OQKV * NPIX + (size_t)(HID + h * DK) * NPIX + chunk * 1024;
    const float* vbase = qkv + (size_t)b * OQKV * NPIX + (size_t)(2 * HID + h * DK) * NPIX + chunk * 1024;

    int ns = t >> 6, dg = t & 7, eg = (t >> 3) & 7;
    float acc[4][4];
#pragma unroll
    for (int i = 0; i < 4; i++)
#pragma unroll
        for (int j = 0; j < 4; j++) acc[i][j] = 0.f;

    for (int n0 = 0; n0 < 1024; n0 += 128) {
#pragma unroll
        for (int q = 0; q < 4; q++) {           // 1024 float4 per array
            int f = t + q * 256;
            int d = f >> 5, c4 = f & 31;
            float km = kms[d], ki = kis[d];
            float4 kv = *(const float4*)(kbase + (size_t)d * NPIX + n0 + c4 * 4);
            Ks[d][c4 * 4 + 0] = __expf(kv.x - km) * ki;
            Ks[d][c4 * 4 + 1] = __expf(kv.y - km) * ki;
            Ks[d][c4 * 4 + 2] = __expf(kv.z - km) * ki;
            Ks[d][c4 * 4 + 3] = __expf(kv.w - km) * ki;
            float4 vv = *(const float4*)(vbase + (size_t)d * NPIX + n0 + c4 * 4);
            Vs[d][c4 * 4 + 0] = vv.x; Vs[d][c4 * 4 + 1] = vv.y;
            Vs[d][c4 * 4 + 2] = vv.z; Vs[d][c4 * 4 + 3] = vv.w;
        }
        __syncthreads();
#pragma unroll 4
        for (int nn = 0; nn < 32; nn++) {
            int n = ns * 32 + nn;
            float kv[4], vv[4];
#pragma unroll
            for (int i = 0; i < 4; i++) kv[i] = Ks[dg * 4 + i][n];
#pragma unroll
            for (int j = 0; j < 4; j++) vv[j] = Vs[eg * 4 + j][n];
#pragma unroll
            for (int i = 0; i < 4; i++)
#pragma unroll
                for (int j = 0; j < 4; j++)
                    acc[i][j] = fmaf(kv[i], vv[j], acc[i][j]);
        }
        __syncthreads();
    }
#pragma unroll
    for (int i = 0; i < 4; i++)
#pragma unroll
        for (int j = 0; j < 4; j++) ctxp[ns][dg * 4 + i][eg * 4 + j] = acc[i][j];
    __syncthreads();
#pragma unroll
    for (int q = 0; q < 4; q++) {
        int idx = t * 4 + q;
        int d = idx >> 5, e = idx & 31;
        float s = ctxp[0][d][e] + ctxp[1][d][e] + ctxp[2][d][e] + ctxp[3][d][e];
        atomicAdd(&ctx[((size_t)(b * NHEADS + h) * DK + d) * DK + e], s);
    }
}

// ---- K3.5: Wc[b][c][h*32+d] = sum_e w_out[c][h*32+e] * ctx[b,h,d,e] ----
__global__ __launch_bounds__(256) void k_wc(const float* __restrict__ wout,
                                            const float* __restrict__ ctx,
                                            float* __restrict__ wc) {
    int b = blockIdx.x;
    int idx = blockIdx.y * 256 + threadIdx.x;   // 0..24575
    int c = idx >> 7, hd = idx & 127;
    int h = hd >> 5, d = hd & 31;
    const float* wrow = wout + (size_t)c * HID + h * DK;
    const float* crow = ctx + ((size_t)(b * NHEADS + h) * DK + d) * DK;
    float s = 0.f;
#pragma unroll
    for (int e = 0; e < DK; e++) s = fmaf(wrow[e], crow[e], s);
    wc[((size_t)b * N_CH + c) * HID + hd] = s;
}

// ---- K4: out_pre = Wc[b] @ softmax_d(q)*scale + b_out ; accumulate LN sums ----
// 64(c) x 64(n) tile, 16x16 threads, 4x4 per thread.
__global__ __launch_bounds__(256) void k_out(const float* __restrict__ qkv,
                                             const float* __restrict__ wc,
                                             const float* __restrict__ bout,
                                             float* __restrict__ out,
                                             double* __restrict__ sums) {
    __shared__ __align__(16) float Wcs[128][64];
    __shared__ __align__(16) float Qs[128][64];
    int t = threadIdx.x;
    int tx = t & 15, ty = t >> 4;    // tx: n/4, ty: c/4
    int n0 = blockIdx.x * 64;
    int c0 = blockIdx.y * 64;
    int b  = blockIdx.z;

    const float* wcb = wc + (size_t)b * N_CH * HID + (size_t)c0 * HID;
#pragma unroll
    for (int q = 0; q < 8; q++) {               // Wc tile -> Wcs[k][o], 64 o x 128 k
        int f = t + q * 256;                    // 2048 float4
        int o = f >> 5, kq = f & 31;
        float4 v = *(const float4*)(wcb + (size_t)o * HID + kq * 4);
        Wcs[kq * 4 + 0][o] = v.x; Wcs[kq * 4 + 1][o] = v.y;
        Wcs[kq * 4 + 2][o] = v.z; Wcs[kq * 4 + 3][o] = v.w;
    }
    const float* qb = qkv + (size_t)b * OQKV * NPIX + n0;
#pragma unroll
    for (int q = 0; q < 8; q++) {               // q tile -> Qs[j][col], 128 j x 64 n
        int f = t + q * 256;
        int j = f >> 4, c4 = f & 15;
        *(float4*)&Qs[j][c4 * 4] = *(const float4*)(qb + (size_t)j * NPIX + c4 * 4);
    }
    __syncthreads();
    {   // q softmax over d per (head, col), *scale
        int col = t & 63, h = t >> 6;
        float m = -1e30f;
#pragma unroll
        for (int d = 0; d < 32; d++) m = fmaxf(m, Qs[h * 32 + d][col]);
        float e[32]; float s = 0.f;
#pragma unroll
        for (int d = 0; d < 32; d++) { e[d] = __expf(Qs[h * 32 + d][col] - m); s += e[d]; }
        float inv = SCALE / s;
#pragma unroll
        for (int d = 0; d < 32; d++) Qs[h * 32 + d][col] = e[d] * inv;
    }
    __syncthreads();

    float acc[4][4];
#pragma unroll
    for (int i = 0; i < 4; i++)
#pragma unroll
        for (int j = 0; j < 4; j++) acc[i][j] = 0.f;
#pragma unroll 4
    for (int k = 0; k < 128; k++) {
        float a[4], bb[4];
        *(float4*)&a[0]  = *(float4*)&Wcs[k][ty * 4];
        *(float4*)&bb[0] = *(float4*)&Qs[k][tx * 4];
#pragma unroll
        for (int i = 0; i < 4; i++)
#pragma unroll
            for (int j = 0; j < 4; j++)
                acc[i][j] = fmaf(a[i], bb[j], acc[i][j]);
    }

    double ls1 = 0.0, ls2 = 0.0;
    float* outb = out + (size_t)b * N_CH * NPIX;
#pragma unroll
    for (int i = 0; i < 4; i++) {
        int c = c0 + ty * 4 + i;
        float bo = bout[c];
        float v[4];
#pragma unroll
        for (int j = 0; j < 4; j++) {
            v[j] = acc[i][j] + bo;
            ls1 += (double)v[j];
            ls2 += (double)v[j] * (double)v[j];
        }
        *(float4*)(outb + (size_t)c * NPIX + n0 + tx * 4) = *(float4*)&v[0];
    }
    __syncthreads();
    double* red = (double*)&Qs[0][0];           // reuse LDS (4KB of 32KB)
    red[t] = ls1; red[256 + t] = ls2;
    __syncthreads();
    for (int s = 128; s > 0; s >>= 1) {
        if (t < s) { red[t] += red[t + s]; red[256 + t] += red[256 + t + s]; }
        __syncthreads();
    }
    if (t == 0) { atomicAdd(&sums[b], red[0]); atomicAdd(&sums[16 + b], red[256]); }
}

// ---- K4.5: per-batch mu, rsqrt(var+eps) ----
__global__ void k_stats(const double* __restrict__ sums, float* __restrict__ murs) {
    int t = threadIdx.x;
    if (t < NB) {
        double n  = (double)N_CH * (double)NPIX;
        double mu = sums[t] / n;
        double var = sums[16 + t] / n - mu * mu;
        murs[t]      = (float)mu;
        murs[16 + t] = (float)(1.0 / sqrt(var + (double)EPS));
    }
}

// ---- K5: in-place normalize + gn affine ----
__global__ __launch_bounds__(256) void k_norm(float* __restrict__ out,
                                              const float* __restrict__ murs,
                                              const float* __restrict__ gnw,
                                              const float* __restrict__ gnb) {
    const size_t total4 = (size_t)NB * N_CH * NPIX / 4;
    for (size_t i = (size_t)blockIdx.x * 256 + threadIdx.x; i < total4;
         i += (size_t)gridDim.x * 256) {
        size_t e = i * 4;
        int b = (int)(e / ((size_t)N_CH * NPIX));
        int c = (int)((e % ((size_t)N_CH * NPIX)) / NPIX);
        float mu = murs[b], rs = murs[16 + b];
        float w  = gnw[c] * rs;
        float bb = gnb[c] - mu * w;
        float4 v = ((float4*)out)[i];
        v.x = v.x * w + bb; v.y = v.y * w + bb;
        v.z = v.z * w + bb; v.w = v.w * w + bb;
        ((float4*)out)[i] = v;
    }
}

extern "C" void kernel_launch(void* const* d_in, const int* in_sizes, int n_in,
                              void* d_out, int out_size, void* d_ws, size_t ws_size,
                              hipStream_t stream) {
    const float* x    = (const float*)d_in[0];
    const float* wqkv = (const float*)d_in[1];
    const float* wout = (const float*)d_in[2];
    const float* bout = (const float*)d_in[3];
    const float* gnw  = (const float*)d_in[4];
    const float* gnb  = (const float*)d_in[5];
    float* out = (float*)d_out;
    float* ws  = (float*)d_ws;

    float*  qkv  = ws + QKV_OFF;
    float*  kmax = ws + KMAX_OFF;
    float*  ksum = ws + KSUM_OFF;
    float*  ctx  = ws + CTX_OFF;
    float*  wc   = ws + WC_OFF;
    double* sums = (double*)(ws + SUM_OFF);
    float*  murs = ws + MURS_OFF;

    k_zero<<<dim3((CTX_SZ + 255) / 256), 256, 0, stream>>>(ws);
    k_qkv<<<dim3(NPIX / 128, OQKV / 128, NB), 256, 0, stream>>>(x, wqkv, qkv);
    k_kstats<<<dim3(NB * HID), 256, 0, stream>>>(qkv, kmax, ksum);
    k_ctx<<<dim3(16, NHEADS, NB), 256, 0, stream>>>(qkv, kmax, ksum, ctx);
    k_wc<<<dim3(NB, (N_CH * HID) / 256), 256, 0, stream>>>(wout, ctx, wc);
    k_out<<<dim3(NPIX / 64, N_CH / 64, NB), 256, 0, stream>>>(qkv, wc, bout, out, sums);
    k_stats<<<dim3(1), 64, 0, stream>>>(sums, murs);
    k_norm<<<dim3(4096), 256, 0, stream>>>(out, murs, gnw, gnb);
}